// Round 5
// baseline (154.248 us; speedup 1.0000x reference)
//
#include <hip/hip_runtime.h>
#include <math.h>

#define NT 365
#define NS 2048
#define NH 64
#define NG 128
#define NW 513      // nh*8+1
#define WSTR 520    // padded row stride for w buffer

__device__ __forceinline__ float sigmoidf_(float x) {
    return 1.0f / (1.0f + __expf(-x));
}

// ---------------- Kernel P: fused prep = gemm (blocks 0..255) + forcing ------
// gemm: w = xc @ W^T + b -> [NS, NW] (stride WSTR); j-tile 2 unused -> skipped.
// forcing: (P,E,T1,T2) -> (Ps, Pl, E, relu(Ta)), blocks 256..3175.
__global__ __launch_bounds__(256) void prep_kernel(const float* __restrict__ xc,
                                                   const float* __restrict__ Wm,
                                                   const float* __restrict__ bv,
                                                   float* __restrict__ w,
                                                   const float* __restrict__ x,
                                                   float* __restrict__ f) {
    __shared__ float xcs[64][132];  // +4 pad: breaks bank conflict on column reads
    __shared__ float Wsh[64][132];
    const int tid = threadIdx.x;

    if (blockIdx.x >= 256) {
        // ---- forcing branch ----
        int i = (blockIdx.x - 256) * 256 + tid;   // exactly NT*NS = 2920*256
        float4 v = ((const float4*)x)[i];
        float P = v.x, E = v.y, T1 = v.z, T2 = v.w;
        float Ta = 0.5f * (T1 + T2);
        float rP;
        if (T2 <= 0.0f)       rP = 0.0f;          // mask0 wins (applied last in ref)
        else if (T1 >= 0.0f)  rP = 1.0f;
        else                  rP = 1.0f - acosf((T1 + T2) / (T2 - T1)) * (1.0f / 3.1415f);
        float Ps = (1.0f - rP) * P;
        float Pl = rP * P;
        ((float4*)f)[i] = make_float4(Ps, Pl, E, fmaxf(Ta, 0.0f));
        return;
    }

    // ---- gemm branch: 64(s) x 64(j) tile, K=128 in LDS, 4x4 register block --
    const int sTile = (blockIdx.x >> 3) * 64;                // 32 s-tiles
    const int by = blockIdx.x & 7;
    const int jt = (by >= 2) ? by + 1 : by;                  // skip unused tile 2
    const int jTile = jt * 64;

    for (int i = 0; i < 8; i++) {
        int f4  = tid + i * 256;
        int row = f4 >> 5;
        int c4  = (f4 & 31) * 4;
        float4 v = ((const float4*)(xc + (size_t)(sTile + row) * NG))[f4 & 31];
        xcs[row][c4] = v.x; xcs[row][c4 + 1] = v.y; xcs[row][c4 + 2] = v.z; xcs[row][c4 + 3] = v.w;
        int jr = jTile + row;
        float4 wv = make_float4(0.f, 0.f, 0.f, 0.f);
        if (jr < NW) wv = ((const float4*)(Wm + (size_t)jr * NG))[f4 & 31];
        Wsh[row][c4] = wv.x; Wsh[row][c4 + 1] = wv.y; Wsh[row][c4 + 2] = wv.z; Wsh[row][c4 + 3] = wv.w;
    }
    __syncthreads();

    const int tx = tid & 15, ty = tid >> 4;
    float acc[4][4] = {};
#pragma unroll 4
    for (int k = 0; k < 128; k++) {
        float a0 = xcs[ty][k], a1 = xcs[ty + 16][k], a2 = xcs[ty + 32][k], a3 = xcs[ty + 48][k];
        float b0 = Wsh[tx][k], b1 = Wsh[tx + 16][k], b2 = Wsh[tx + 32][k], b3 = Wsh[tx + 48][k];
        acc[0][0] += a0 * b0; acc[0][1] += a0 * b1; acc[0][2] += a0 * b2; acc[0][3] += a0 * b3;
        acc[1][0] += a1 * b0; acc[1][1] += a1 * b1; acc[1][2] += a1 * b2; acc[1][3] += a1 * b3;
        acc[2][0] += a2 * b0; acc[2][1] += a2 * b1; acc[2][2] += a2 * b2; acc[2][3] += a2 * b3;
        acc[3][0] += a3 * b0; acc[3][1] += a3 * b1; acc[3][2] += a3 * b2; acc[3][3] += a3 * b3;
    }
#pragma unroll
    for (int i = 0; i < 4; i++) {
        int s = sTile + ty + 16 * i;
#pragma unroll
        for (int j = 0; j < 4; j++) {
            int jj = jTile + tx + 16 * j;
            if (jj < NW) w[(size_t)s * WSTR + jj] = acc[i][j] + bv[jj];
        }
    }
}

// ---------------- Kernel C: scan, TWO sites per wave (ILP x2) ----------------
// Per step, per site: ~18 VALU + 1 ds_write into a per-(wave,site) [h][t] tile
// (stride 33 -> 2-way banks, free). Every 32 steps: half-wave per site
// transpose-reduces its tile (64 imm-offset ds_read_b32, 4 accumulators),
// one predicated store. Sites are adjacent -> paired forcing loads.
template <bool PRE>
__global__ __launch_bounds__(256) void scan_kernel(const float* __restrict__ fx,
                                                   const float* __restrict__ w,
                                                   float* __restrict__ Y) {
    __shared__ float ybuf[4][2][64][33];   // 67,584 B per block (4 waves x 2 sites)
    const int wave = threadIdx.x >> 6;
    const int lane = threadIdx.x & 63;
    const int sA = blockIdx.x * 8 + wave * 2;      // sites sA, sA+1
    const float* wrA = w + (size_t)sA * WSTR;
    const float* wrB = wrA + WSTR;

    // ---- gate parameters for both sites (lane = hidden unit) ----
    float gmA = __expf(wrA[lane]) + 1.0f,          gmB = __expf(wrB[lane]) + 1.0f;
    float geNA = -2.0f * sigmoidf_(wrA[64 + lane]), geNB = -2.0f * sigmoidf_(wrB[64 + lane]);
    float k0A = sigmoidf_(wrA[192 + lane]),        k0B = sigmoidf_(wrB[192 + lane]);
    float w4A = wrA[256 + lane],                   w4B = wrB[256 + lane];
    float k1A = sigmoidf_(w4A),                    k1B = sigmoidf_(w4B);
    float k2A = sigmoidf_(wrA[320 + lane]),        k2B = sigmoidf_(wrB[320 + lane]);
    float glA = __expf(wrA[384 + lane]),           glB = __expf(wrB[384 + lane]);
    float kbA = sigmoidf_(wrA[448 + lane]) * 0.1f, kbB = sigmoidf_(wrB[448 + lane]) * 0.1f;
    float wlA = wrA[512],                          wlB = wrB[512];
    float qbA = fmaxf(wlA, 0.0f) * (1.0f / NH),    qbB = fmaxf(wlB, 0.0f) * (1.0f / NH);
    float viA = sigmoidf_(wlA),                    viB = sigmoidf_(wlB);

    // softmax over lanes -> ga (setup, once per site)
    float mA = w4A, mB = w4B;
#pragma unroll
    for (int off = 32; off; off >>= 1) {
        mA = fmaxf(mA, __shfl_xor(mA, off));
        mB = fmaxf(mB, __shfl_xor(mB, off));
    }
    float exA = __expf(w4A - mA), exB = __expf(w4B - mB);
    float smA = exA, smB = exB;
#pragma unroll
    for (int off = 32; off; off >>= 1) {
        smA += __shfl_xor(smA, off);
        smB += __shfl_xor(smB, off);
    }
    float gaA = exA / smA, gaB = exB / smB;

    // folded coefficients
    float c0A = k0A * gaA,                  c0B = k0B * gaB;
    float c1A = k1A * (1.0f - kbA) * gaA,   c1B = k1B * (1.0f - kbB) * gaB;
    float c2A = k2A * gaA,                  c2B = k2B * gaB;
    float k0cA = 1.0f - k0A,                k0cB = 1.0f - k0B;
    float k2cA = 1.0f - k2A,                k2cB = 1.0f - k2B;
    float glNA = -glA,                      glNB = -glB;
    float viCA = 1.0f - viA,                viCB = 1.0f - viB;

    float S0A = 0.f, H0A = 0.f, H1A = 0.f, H2A = 0.f;
    float S0B = 0.f, H0B = 0.f, H1B = 0.f, H2B = 0.f;

    // wave-uniform forcing pointer (scalar -> SMEM loads); sites adjacent
    const int su = __builtin_amdgcn_readfirstlane(sA);
    const float4* fp = (const float4*)fx + su;

    float* wp = &ybuf[wave][0][lane][0];                      // writes: row = h
    const float* rp = &ybuf[wave][lane >> 5][0][lane & 31];   // reads: column
    const float qbS = (lane < 32) ? qbA : qbB;

    float4 vbA[8], vbB[8];
#pragma unroll
    for (int b = 0; b < 8; b++) { vbA[b] = fp[b * NS]; vbB[b] = fp[b * NS + 1]; }

    for (int sb = 0; sb < 12; sb++) {                         // 12*32 = 384 >= NT
        const int t0 = sb * 32;
        for (int ib = 0; ib < 4; ib++) {
#pragma unroll
            for (int b = 0; b < 8; b++) {
                const int tl = ib * 8 + b;
                float4 vA = vbA[b], vB = vbB[b];
                int tn = t0 + (ib + 1) * 8 + b;               // prefetch (clamped)
                tn = tn < NT ? tn : NT - 1;
                vbA[b] = fp[(size_t)tn * NS];
                vbB[b] = fp[(size_t)tn * NS + 1];

                float PsA, PlA, EA, TaRA, PsB, PlB, EB, TaRB;
                if (PRE) {
                    PsA = vA.x; PlA = vA.y; EA = vA.z; TaRA = vA.w;
                    PsB = vB.x; PlB = vB.y; EB = vB.z; TaRB = vB.w;
                } else {
                    {
                        float P = vA.x; EA = vA.y;
                        float T1 = vA.z, T2 = vA.w;
                        float Ta = 0.5f * (T1 + T2);
                        float rP;
                        if (T2 <= 0.0f)      rP = 0.0f;
                        else if (T1 >= 0.0f) rP = 1.0f;
                        else                 rP = 1.0f - acosf((T1 + T2) / (T2 - T1)) * (1.0f / 3.1415f);
                        PsA = (1.0f - rP) * P; PlA = rP * P; TaRA = fmaxf(Ta, 0.0f);
                    }
                    {
                        float P = vB.x; EB = vB.y;
                        float T1 = vB.z, T2 = vB.w;
                        float Ta = 0.5f * (T1 + T2);
                        float rP;
                        if (T2 <= 0.0f)      rP = 0.0f;
                        else if (T1 >= 0.0f) rP = 1.0f;
                        else                 rP = 1.0f - acosf((T1 + T2) / (T2 - T1)) * (1.0f / 3.1415f);
                        PsB = (1.0f - rP) * P; PlB = rP * P; TaRB = fmaxf(Ta, 0.0f);
                    }
                }
                // site A
                float SA   = S0A + PsA;
                float SmA  = fminf(S0A, gmA * TaRA);
                S0A = SA - SmA;
                float G1A  = fmaxf(H1A + SmA + fmaf(EA, geNA, PlA * viA), 0.0f);
                float G0A  = fmaxf(H0A + G1A + fmaf(PlA, viCA, glNA), 0.0f);
                float m1A  = fminf(G1A, glA);
                float Q1aA = m1A * k1A;
                float G2A  = fmaf(Q1aA, kbA, H2A);
                wp[tl] = fmaf(G0A, c0A, fmaf(m1A, c1A, G2A * c2A));
                H0A = G0A * k0cA;
                H1A = fminf(G1A - Q1aA, glA);
                H2A = G2A * k2cA;
                // site B
                float SB   = S0B + PsB;
                float SmB  = fminf(S0B, gmB * TaRB);
                S0B = SB - SmB;
                float G1B  = fmaxf(H1B + SmB + fmaf(EB, geNB, PlB * viB), 0.0f);
                float G0B  = fmaxf(H0B + G1B + fmaf(PlB, viCB, glNB), 0.0f);
                float m1B  = fminf(G1B, glB);
                float Q1aB = m1B * k1B;
                float G2B  = fmaf(Q1aB, kbB, H2B);
                wp[64 * 33 + tl] = fmaf(G0B, c0B, fmaf(m1B, c1B, G2B * c2B));
                H0B = G0B * k0cB;
                H1B = fminf(G1B - Q1aB, glB);
                H2B = G2B * k2cB;
            }
        }
        // transpose-reduce: half-wave per site; lane sums 64 h of column (lane&31)
        float a0 = 0.f, a1 = 0.f, a2 = 0.f, a3 = 0.f;
#pragma unroll
        for (int j = 0; j < 64; j += 4) {
            a0 += rp[(size_t)j * 33];
            a1 += rp[(size_t)(j + 1) * 33];
            a2 += rp[(size_t)(j + 2) * 33];
            a3 += rp[(size_t)(j + 3) * 33];
        }
        float full = (a0 + a1) + (a2 + a3);
        int t = t0 + (lane & 31);
        if (t < NT) Y[(size_t)t * NS + sA + (lane >> 5)] = full + qbS;
    }
}

extern "C" void kernel_launch(void* const* d_in, const int* in_sizes, int n_in,
                              void* d_out, int out_size, void* d_ws, size_t ws_size,
                              hipStream_t stream) {
    const float* x  = (const float*)d_in[0];   // [NT, NS, 4]
    const float* xc = (const float*)d_in[1];   // [NS, NG]
    const float* Wm = (const float*)d_in[2];   // [NW, NG]
    const float* bv = (const float*)d_in[3];   // [NW]
    float* out = (float*)d_out;                // [NT, NS] fp32

    float* wbuf = (float*)d_ws;                                 // NS*WSTR floats
    size_t wbytes = (size_t)NS * WSTR * sizeof(float);          // 4,259,840 B
    float* fbuf = (float*)((char*)d_ws + wbytes);               // NT*NS float4
    size_t need = wbytes + (size_t)NT * NS * 4 * sizeof(float); // ~16.2 MB

    if (ws_size >= need) {
        prep_kernel<<<256 + (NT * NS) / 256, 256, 0, stream>>>(xc, Wm, bv, wbuf, x, fbuf);
        scan_kernel<true><<<NS / 8, 256, 0, stream>>>(fbuf, wbuf, out);
    } else {
        prep_kernel<<<256, 256, 0, stream>>>(xc, Wm, bv, wbuf, x, fbuf);  // gemm only
        scan_kernel<false><<<NS / 8, 256, 0, stream>>>(x, wbuf, out);
    }
}

// Round 6
// 110.119 us; speedup vs baseline: 1.4007x; 1.4007x over previous
//
#include <hip/hip_runtime.h>
#include <math.h>

#define NT 365
#define NS 2048
#define NH 64
#define NG 128
#define NW 513      // nh*8+1
#define WSTR 520    // padded row stride for w buffer

__device__ __forceinline__ float sigmoidf_(float x) {
    return 1.0f / (1.0f + __expf(-x));
}

// ---------------- Kernel P: fused prep = gemm (blocks 0..255) + forcing ------
__global__ __launch_bounds__(256) void prep_kernel(const float* __restrict__ xc,
                                                   const float* __restrict__ Wm,
                                                   const float* __restrict__ bv,
                                                   float* __restrict__ w,
                                                   const float* __restrict__ x,
                                                   float* __restrict__ f) {
    __shared__ float xcs[64][132];  // +4 pad: breaks bank conflict on column reads
    __shared__ float Wsh[64][132];
    const int tid = threadIdx.x;

    if (blockIdx.x >= 256) {
        // ---- forcing branch: (P,E,T1,T2) -> (Ps,Pl,E,relu(Ta)) ----
        int i = (blockIdx.x - 256) * 256 + tid;   // exactly NT*NS = 2920*256
        float4 v = ((const float4*)x)[i];
        float P = v.x, E = v.y, T1 = v.z, T2 = v.w;
        float Ta = 0.5f * (T1 + T2);
        float rP;
        if (T2 <= 0.0f)       rP = 0.0f;          // mask0 wins (applied last in ref)
        else if (T1 >= 0.0f)  rP = 1.0f;
        else                  rP = 1.0f - acosf((T1 + T2) / (T2 - T1)) * (1.0f / 3.1415f);
        float Ps = (1.0f - rP) * P;
        float Pl = rP * P;
        ((float4*)f)[i] = make_float4(Ps, Pl, E, fmaxf(Ta, 0.0f));
        return;
    }

    // ---- gemm branch: w = xc @ W^T + b; 64x64 tile, K=128 in LDS ----
    const int sTile = (blockIdx.x >> 3) * 64;                // 32 s-tiles
    const int by = blockIdx.x & 7;
    const int jt = (by >= 2) ? by + 1 : by;                  // skip unused j-tile 2
    const int jTile = jt * 64;

    for (int i = 0; i < 8; i++) {
        int f4  = tid + i * 256;
        int row = f4 >> 5;
        int c4  = (f4 & 31) * 4;
        float4 v = ((const float4*)(xc + (size_t)(sTile + row) * NG))[f4 & 31];
        xcs[row][c4] = v.x; xcs[row][c4 + 1] = v.y; xcs[row][c4 + 2] = v.z; xcs[row][c4 + 3] = v.w;
        int jr = jTile + row;
        float4 wv = make_float4(0.f, 0.f, 0.f, 0.f);
        if (jr < NW) wv = ((const float4*)(Wm + (size_t)jr * NG))[f4 & 31];
        Wsh[row][c4] = wv.x; Wsh[row][c4 + 1] = wv.y; Wsh[row][c4 + 2] = wv.z; Wsh[row][c4 + 3] = wv.w;
    }
    __syncthreads();

    const int tx = tid & 15, ty = tid >> 4;
    float acc[4][4] = {};
#pragma unroll 4
    for (int k = 0; k < 128; k++) {
        float a0 = xcs[ty][k], a1 = xcs[ty + 16][k], a2 = xcs[ty + 32][k], a3 = xcs[ty + 48][k];
        float b0 = Wsh[tx][k], b1 = Wsh[tx + 16][k], b2 = Wsh[tx + 32][k], b3 = Wsh[tx + 48][k];
        acc[0][0] += a0 * b0; acc[0][1] += a0 * b1; acc[0][2] += a0 * b2; acc[0][3] += a0 * b3;
        acc[1][0] += a1 * b0; acc[1][1] += a1 * b1; acc[1][2] += a1 * b2; acc[1][3] += a1 * b3;
        acc[2][0] += a2 * b0; acc[2][1] += a2 * b1; acc[2][2] += a2 * b2; acc[2][3] += a2 * b3;
        acc[3][0] += a3 * b0; acc[3][1] += a3 * b1; acc[3][2] += a3 * b2; acc[3][3] += a3 * b3;
    }
#pragma unroll
    for (int i = 0; i < 4; i++) {
        int s = sTile + ty + 16 * i;
#pragma unroll
        for (int j = 0; j < 4; j++) {
            int jj = jTile + tx + 16 * j;
            if (jj < NW) w[(size_t)s * WSTR + jj] = acc[i][j] + bv[jj];
        }
    }
}

// ---------------- Kernel C: scan, one site per wave, vector prefetch ---------
// Forcing prefetch uses LAUNDERED (forced-VGPR) addresses so loads stay in the
// vmcnt domain: counted vmcnt waits on 8-step-ahead prefetch never stall and
// never drain the per-step ds_write (lgkm). 32-step superblocks fully unrolled;
// per-wave [64][33] LDS tile; transpose-reduce every 32 steps.
template <bool PRE>
__global__ __launch_bounds__(256) void scan_kernel(const float* __restrict__ fx,
                                                   const float* __restrict__ w,
                                                   float* __restrict__ Y) {
    __shared__ float ybuf[4][64][33];   // 33,792 B per block
    const int wave = threadIdx.x >> 6;
    const int lane = threadIdx.x & 63;
    const int s = blockIdx.x * 4 + wave;
    const float* wr = w + (size_t)s * WSTR;

    // gate parameters (lane = hidden unit) — scalar loads OK (setup only)
    float gm = __expf(wr[lane]) + 1.0f;
    float geN = -2.0f * sigmoidf_(wr[64 + lane]);
    float k0 = sigmoidf_(wr[192 + lane]);
    float w4 = wr[256 + lane];
    float k1 = sigmoidf_(w4);
    float k2 = sigmoidf_(wr[320 + lane]);
    float gl = __expf(wr[384 + lane]);
    float kb = sigmoidf_(wr[448 + lane]) * 0.1f;
    float wl = wr[512];
    float qb = fmaxf(wl, 0.0f) * (1.0f / (float)NH);
    float vi = sigmoidf_(wl);

    // softmax over lanes -> ga
    float m = w4;
#pragma unroll
    for (int off = 32; off; off >>= 1) m = fmaxf(m, __shfl_xor(m, off));
    float ex = __expf(w4 - m);
    float sum = ex;
#pragma unroll
    for (int off = 32; off; off >>= 1) sum += __shfl_xor(sum, off);
    float ga = ex / sum;

    // folded coefficients
    float c0  = k0 * ga;
    float c1  = k1 * (1.0f - kb) * ga;
    float c2  = k2 * ga;
    float k0c = 1.0f - k0;
    float k2c = 1.0f - k2;
    float glN = -gl;
    float viC = 1.0f - vi;

    float S0 = 0.f, H0 = 0.f, H1 = 0.f, H2 = 0.f;

    // LAUNDER the site index: force it into a VGPR so the compiler cannot
    // scalarize the forcing loads into SMEM (which would put them on lgkmcnt
    // and serialize against every step's ds_write).
    int sv = s;
    asm volatile("" : "+v"(sv));
    const float4* fp = (const float4*)fx + sv;

    float* wp = &ybuf[wave][lane][0];                         // write: row h=lane
    const float* rp = &ybuf[wave][(lane >> 5) << 5][lane & 31]; // read: column

    float4 vbuf[8];
#pragma unroll
    for (int b = 0; b < 8; b++) vbuf[b] = fp[b * NS];

#define STEP_BODY(vv, tl)                                                      \
    {                                                                          \
        float Ps, Pl, E, TaR;                                                  \
        if (PRE) { Ps = vv.x; Pl = vv.y; E = vv.z; TaR = vv.w; }               \
        else {                                                                 \
            float P = vv.x; E = vv.y;                                          \
            float T1 = vv.z, T2 = vv.w;                                        \
            float Ta = 0.5f * (T1 + T2);                                       \
            float rP;                                                          \
            if (T2 <= 0.0f)      rP = 0.0f;                                    \
            else if (T1 >= 0.0f) rP = 1.0f;                                    \
            else rP = 1.0f - acosf((T1 + T2) / (T2 - T1)) * (1.0f / 3.1415f);  \
            Ps = (1.0f - rP) * P; Pl = rP * P; TaR = fmaxf(Ta, 0.0f);          \
        }                                                                      \
        float S   = S0 + Ps;                                                   \
        float Sm  = fminf(S0, gm * TaR);                                       \
        S0 = S - Sm;                                                           \
        float G1  = fmaxf(H1 + Sm + fmaf(E, geN, Pl * vi), 0.0f);              \
        float G0  = fmaxf(H0 + G1 + fmaf(Pl, viC, glN), 0.0f);                 \
        float m1  = fminf(G1, gl);                                             \
        float Q1a = m1 * k1;                                                   \
        float G2  = fmaf(Q1a, kb, H2);                                         \
        wp[tl] = fmaf(G0, c0, fmaf(m1, c1, G2 * c2));                          \
        H0 = G0 * k0c;                                                         \
        H1 = fminf(G1 - Q1a, gl);                                              \
        H2 = G2 * k2c;                                                         \
    }

#define TRRED(t0)                                                              \
    {                                                                          \
        float a0 = 0.f, a1 = 0.f, a2 = 0.f, a3 = 0.f;                          \
        _Pragma("unroll")                                                      \
        for (int j = 0; j < 32; j += 4) {                                      \
            a0 += rp[(size_t)j * 33];                                          \
            a1 += rp[(size_t)(j + 1) * 33];                                    \
            a2 += rp[(size_t)(j + 2) * 33];                                    \
            a3 += rp[(size_t)(j + 3) * 33];                                    \
        }                                                                      \
        float part = (a0 + a1) + (a2 + a3);                                    \
        float full = part + __shfl_xor(part, 32);                              \
        int t = (t0) + (lane & 31);                                            \
        if (lane < 32 && t < NT) Y[(size_t)t * NS + s] = full + qb;            \
    }

    // superblocks 0..10: prefetch indices t0+8..t0+39 <= 359 < NT, no clamp
    for (int sb = 0; sb < 11; ++sb) {
        const int t0 = sb * 32;
        const float4* fpt = fp + (size_t)t0 * NS;
#pragma unroll
        for (int tl = 0; tl < 32; ++tl) {
            float4 v = vbuf[tl & 7];
            vbuf[tl & 7] = fpt[(size_t)(tl + 8) * NS];     // prefetch t0+tl+8
            STEP_BODY(v, tl);
        }
        TRRED(t0);
    }
    // tail superblock (t0=352): steps 352..383, stores masked to t<365,
    // prefetch index clamped to NT-1 (loads valid data, results discarded)
    {
        const int t0 = 352;
#pragma unroll
        for (int tl = 0; tl < 32; ++tl) {
            float4 v = vbuf[tl & 7];
            int tn = t0 + tl + 8; tn = tn < NT ? tn : NT - 1;
            vbuf[tl & 7] = fp[(size_t)tn * NS];
            STEP_BODY(v, tl);
        }
        TRRED(t0);
    }
#undef STEP_BODY
#undef TRRED
}

extern "C" void kernel_launch(void* const* d_in, const int* in_sizes, int n_in,
                              void* d_out, int out_size, void* d_ws, size_t ws_size,
                              hipStream_t stream) {
    const float* x  = (const float*)d_in[0];   // [NT, NS, 4]
    const float* xc = (const float*)d_in[1];   // [NS, NG]
    const float* Wm = (const float*)d_in[2];   // [NW, NG]
    const float* bv = (const float*)d_in[3];   // [NW]
    float* out = (float*)d_out;                // [NT, NS] fp32

    float* wbuf = (float*)d_ws;                                 // NS*WSTR floats
    size_t wbytes = (size_t)NS * WSTR * sizeof(float);          // 4,259,840 B
    float* fbuf = (float*)((char*)d_ws + wbytes);               // NT*NS float4
    size_t need = wbytes + (size_t)NT * NS * 4 * sizeof(float); // ~16.2 MB

    if (ws_size >= need) {
        prep_kernel<<<256 + (NT * NS) / 256, 256, 0, stream>>>(xc, Wm, bv, wbuf, x, fbuf);
        scan_kernel<true><<<NS / 4, 256, 0, stream>>>(fbuf, wbuf, out);
    } else {
        prep_kernel<<<256, 256, 0, stream>>>(xc, Wm, bv, wbuf, x, fbuf);  // gemm only
        scan_kernel<false><<<NS / 4, 256, 0, stream>>>(x, wbuf, out);
    }
}

// Round 7
// 107.802 us; speedup vs baseline: 1.4308x; 1.0215x over previous
//
#include <hip/hip_runtime.h>
#include <math.h>

#define NT 365
#define NS 2048
#define NH 64
#define NG 128
#define NW 513      // nh*8+1
#define WSTR 520    // padded row stride for w buffer

__device__ __forceinline__ float sigmoidf_(float x) {
    return 1.0f / (1.0f + __expf(-x));
}

// ---------------- Kernel P: fused prep = gemm (blocks 0..255) + forcing ------
__global__ __launch_bounds__(256) void prep_kernel(const float* __restrict__ xc,
                                                   const float* __restrict__ Wm,
                                                   const float* __restrict__ bv,
                                                   float* __restrict__ w,
                                                   const float* __restrict__ x,
                                                   float* __restrict__ f) {
    __shared__ float xcs[64][132];  // +4 pad: breaks bank conflict on column reads
    __shared__ float Wsh[64][132];
    const int tid = threadIdx.x;

    if (blockIdx.x >= 256) {
        // ---- forcing branch: (P,E,T1,T2) -> (Ps,Pl,E,relu(Ta)) ----
        int i = (blockIdx.x - 256) * 256 + tid;   // exactly NT*NS = 2920*256
        float4 v = ((const float4*)x)[i];
        float P = v.x, E = v.y, T1 = v.z, T2 = v.w;
        float Ta = 0.5f * (T1 + T2);
        float rP;
        if (T2 <= 0.0f)       rP = 0.0f;          // mask0 wins (applied last in ref)
        else if (T1 >= 0.0f)  rP = 1.0f;
        else                  rP = 1.0f - acosf((T1 + T2) / (T2 - T1)) * (1.0f / 3.1415f);
        float Ps = (1.0f - rP) * P;
        float Pl = rP * P;
        ((float4*)f)[i] = make_float4(Ps, Pl, E, fmaxf(Ta, 0.0f));
        return;
    }

    // ---- gemm branch: w = xc @ W^T + b; 64x64 tile, K=128 in LDS ----
    const int sTile = (blockIdx.x >> 3) * 64;                // 32 s-tiles
    const int by = blockIdx.x & 7;
    const int jt = (by >= 2) ? by + 1 : by;                  // skip unused j-tile 2
    const int jTile = jt * 64;

    for (int i = 0; i < 8; i++) {
        int f4  = tid + i * 256;
        int row = f4 >> 5;
        int c4  = (f4 & 31) * 4;
        float4 v = ((const float4*)(xc + (size_t)(sTile + row) * NG))[f4 & 31];
        xcs[row][c4] = v.x; xcs[row][c4 + 1] = v.y; xcs[row][c4 + 2] = v.z; xcs[row][c4 + 3] = v.w;
        int jr = jTile + row;
        float4 wv = make_float4(0.f, 0.f, 0.f, 0.f);
        if (jr < NW) wv = ((const float4*)(Wm + (size_t)jr * NG))[f4 & 31];
        Wsh[row][c4] = wv.x; Wsh[row][c4 + 1] = wv.y; Wsh[row][c4 + 2] = wv.z; Wsh[row][c4 + 3] = wv.w;
    }
    __syncthreads();

    const int tx = tid & 15, ty = tid >> 4;
    float acc[4][4] = {};
#pragma unroll 4
    for (int k = 0; k < 128; k++) {
        float a0 = xcs[ty][k], a1 = xcs[ty + 16][k], a2 = xcs[ty + 32][k], a3 = xcs[ty + 48][k];
        float b0 = Wsh[tx][k], b1 = Wsh[tx + 16][k], b2 = Wsh[tx + 32][k], b3 = Wsh[tx + 48][k];
        acc[0][0] += a0 * b0; acc[0][1] += a0 * b1; acc[0][2] += a0 * b2; acc[0][3] += a0 * b3;
        acc[1][0] += a1 * b0; acc[1][1] += a1 * b1; acc[1][2] += a1 * b2; acc[1][3] += a1 * b3;
        acc[2][0] += a2 * b0; acc[2][1] += a2 * b1; acc[2][2] += a2 * b2; acc[2][3] += a2 * b3;
        acc[3][0] += a3 * b0; acc[3][1] += a3 * b1; acc[3][2] += a3 * b2; acc[3][3] += a3 * b3;
    }
#pragma unroll
    for (int i = 0; i < 4; i++) {
        int s = sTile + ty + 16 * i;
#pragma unroll
        for (int j = 0; j < 4; j++) {
            int jj = jTile + tx + 16 * j;
            if (jj < NW) w[(size_t)s * WSTR + jj] = acc[i][j] + bv[jj];
        }
    }
}

// ---------------- Kernel C: scan, one site per wave ---------------------------
// Forcing loads: uniform SGPR base + laundered 32-bit rolling byte offsets ->
// global_load_dwordx4 saddr+voffset, 1 v_add_u32 per step, vmcnt domain only.
// Folded algebra: G2=fma(m1,k1*kb,H2), H1=min(fma(m1,-k1,G1),gl) (Q1a removed).
// 32-step superblocks fully unrolled; per-wave [64][33] LDS tile;
// transpose-reduce every 32 steps (imm-offset ds_read_b32, no cross-lane).
template <bool PRE>
__global__ __launch_bounds__(256) void scan_kernel(const float* __restrict__ fx,
                                                   const float* __restrict__ w,
                                                   float* __restrict__ Y) {
    __shared__ float ybuf[4][64][33];   // 33,792 B per block
    const int wave = threadIdx.x >> 6;
    const int lane = threadIdx.x & 63;
    const int s = blockIdx.x * 4 + wave;
    const float* wr = w + (size_t)s * WSTR;

    // gate parameters (lane = hidden unit) — scalar loads OK (setup only)
    float gm = __expf(wr[lane]) + 1.0f;
    float geN = -2.0f * sigmoidf_(wr[64 + lane]);
    float k0 = sigmoidf_(wr[192 + lane]);
    float w4 = wr[256 + lane];
    float k1 = sigmoidf_(w4);
    float k2 = sigmoidf_(wr[320 + lane]);
    float gl = __expf(wr[384 + lane]);
    float kb = sigmoidf_(wr[448 + lane]) * 0.1f;
    float wl = wr[512];
    float qb = fmaxf(wl, 0.0f) * (1.0f / (float)NH);
    float vi = sigmoidf_(wl);

    // softmax over lanes -> ga
    float m = w4;
#pragma unroll
    for (int off = 32; off; off >>= 1) m = fmaxf(m, __shfl_xor(m, off));
    float ex = __expf(w4 - m);
    float sum = ex;
#pragma unroll
    for (int off = 32; off; off >>= 1) sum += __shfl_xor(sum, off);
    float ga = ex / sum;

    // folded coefficients
    float c0   = k0 * ga;
    float c1   = k1 * (1.0f - kb) * ga;
    float c2   = k2 * ga;
    float k0c  = 1.0f - k0;
    float k2c  = 1.0f - k2;
    float glN  = -gl;
    float viC  = 1.0f - vi;
    float k1kb = k1 * kb;    // G2 = fma(m1, k1kb, H2)
    float k1N  = -k1;        // H1 = min(fma(m1, k1N, G1), gl)

    float S0 = 0.f, H0 = 0.f, H1 = 0.f, H2 = 0.f;

    // Forcing loads: keep base UNIFORM (SGPR pair) and launder only the
    // 32-bit byte offset into a VGPR -> saddr+voffset global_load_dwordx4,
    // vmcnt domain (never collides with the per-step ds_write's lgkmcnt).
    const char* fb = (const char*)fx;
    unsigned off0 = (unsigned)s * 16u;
    asm volatile("" : "+v"(off0));
    unsigned offs[8];
    float4 vbuf[8];
#pragma unroll
    for (int b = 0; b < 8; b++) {
        offs[b] = off0 + (unsigned)(b * NS * 16);
        vbuf[b] = *(const float4*)(fb + offs[b]);
        offs[b] += 8u * NS * 16u;           // next use: t = b + 8
    }

    float* wp = &ybuf[wave][lane][0];                           // write: row h=lane
    const float* rp = &ybuf[wave][(lane >> 5) << 5][lane & 31]; // read: column

#define STEP_COMP(vv, tl)                                                      \
    {                                                                          \
        float Ps, Pl, E, TaR;                                                  \
        if (PRE) { Ps = vv.x; Pl = vv.y; E = vv.z; TaR = vv.w; }               \
        else {                                                                 \
            float P = vv.x; E = vv.y;                                          \
            float T1 = vv.z, T2 = vv.w;                                        \
            float Ta = 0.5f * (T1 + T2);                                       \
            float rP;                                                          \
            if (T2 <= 0.0f)      rP = 0.0f;                                    \
            else if (T1 >= 0.0f) rP = 1.0f;                                    \
            else rP = 1.0f - acosf((T1 + T2) / (T2 - T1)) * (1.0f / 3.1415f);  \
            Ps = (1.0f - rP) * P; Pl = rP * P; TaR = fmaxf(Ta, 0.0f);          \
        }                                                                      \
        float S   = S0 + Ps;                                                   \
        float Sm  = fminf(S0, gm * TaR);                                       \
        S0 = S - Sm;                                                           \
        float G1  = fmaxf(H1 + Sm + fmaf(E, geN, Pl * vi), 0.0f);              \
        float G0  = fmaxf(H0 + G1 + fmaf(Pl, viC, glN), 0.0f);                 \
        float m1  = fminf(G1, gl);                                             \
        float G2  = fmaf(m1, k1kb, H2);                                        \
        wp[tl] = fmaf(G0, c0, fmaf(m1, c1, G2 * c2));                          \
        H0 = G0 * k0c;                                                         \
        H1 = fminf(fmaf(m1, k1N, G1), gl);                                     \
        H2 = G2 * k2c;                                                         \
    }

#define TRRED(t0)                                                              \
    {                                                                          \
        float a0 = 0.f, a1 = 0.f, a2 = 0.f, a3 = 0.f;                          \
        _Pragma("unroll")                                                      \
        for (int j = 0; j < 32; j += 4) {                                      \
            a0 += rp[(size_t)j * 33];                                          \
            a1 += rp[(size_t)(j + 1) * 33];                                    \
            a2 += rp[(size_t)(j + 2) * 33];                                    \
            a3 += rp[(size_t)(j + 3) * 33];                                    \
        }                                                                      \
        float part = (a0 + a1) + (a2 + a3);                                    \
        float full = part + __shfl_xor(part, 32);                              \
        int t = (t0) + (lane & 31);                                            \
        if (lane < 32 && t < NT) Y[(size_t)t * NS + s] = full + qb;            \
    }

    // superblocks 0..10: prefetch t0+tl+8 <= 359 < NT, rolling offsets
    for (int sb = 0; sb < 11; ++sb) {
#pragma unroll
        for (int tl = 0; tl < 32; ++tl) {
            float4 v = vbuf[tl & 7];
            vbuf[tl & 7] = *(const float4*)(fb + offs[tl & 7]);  // prefetch
            offs[tl & 7] += 8u * NS * 16u;
            STEP_COMP(v, tl);
        }
        TRRED(sb * 32);
    }
    // tail superblock (t0=352): steps 352..383; stores masked to t<365;
    // prefetch offsets computed fresh with clamped t (no OOB in any path)
    {
        const int t0 = 352;
#pragma unroll
        for (int tl = 0; tl < 32; ++tl) {
            float4 v = vbuf[tl & 7];
            int tn = t0 + tl + 8; tn = tn < NT ? tn : NT - 1;
            vbuf[tl & 7] = *(const float4*)(fb + (off0 + (unsigned)(tn * NS * 16)));
            STEP_COMP(v, tl);
        }
        TRRED(t0);
    }
#undef STEP_COMP
#undef TRRED
}

extern "C" void kernel_launch(void* const* d_in, const int* in_sizes, int n_in,
                              void* d_out, int out_size, void* d_ws, size_t ws_size,
                              hipStream_t stream) {
    const float* x  = (const float*)d_in[0];   // [NT, NS, 4]
    const float* xc = (const float*)d_in[1];   // [NS, NG]
    const float* Wm = (const float*)d_in[2];   // [NW, NG]
    const float* bv = (const float*)d_in[3];   // [NW]
    float* out = (float*)d_out;                // [NT, NS] fp32

    float* wbuf = (float*)d_ws;                                 // NS*WSTR floats
    size_t wbytes = (size_t)NS * WSTR * sizeof(float);          // 4,259,840 B
    float* fbuf = (float*)((char*)d_ws + wbytes);               // NT*NS float4
    size_t need = wbytes + (size_t)NT * NS * 4 * sizeof(float); // ~16.2 MB

    if (ws_size >= need) {
        prep_kernel<<<256 + (NT * NS) / 256, 256, 0, stream>>>(xc, Wm, bv, wbuf, x, fbuf);
        scan_kernel<true><<<NS / 4, 256, 0, stream>>>(fbuf, wbuf, out);
    } else {
        prep_kernel<<<256, 256, 0, stream>>>(xc, Wm, bv, wbuf, x, fbuf);  // gemm only
        scan_kernel<false><<<NS / 4, 256, 0, stream>>>(x, wbuf, out);
    }
}